// Round 9
// baseline (234.785 us; speedup 1.0000x reference)
//
#include <hip/hip_runtime.h>
#include <stdint.h>

#define NUM_NODES 50000
#define B_ 4096
#define N_ 100

typedef float f32x4 __attribute__((ext_vector_type(4)));
typedef float f32x2 __attribute__((ext_vector_type(2)));
typedef short s16x8 __attribute__((ext_vector_type(8)));

__device__ inline unsigned short f2bf(float f) {
    unsigned u = __float_as_uint(f);
    u += 0x7fffu + ((u >> 16) & 1u);
    return (unsigned short)(u >> 16);
}

// wave64 sum-reduce on the VALU pipe (DPP), result broadcast to all lanes.
template <int CTRL>
__device__ inline float dpp_add(float x) {
    int t = __builtin_amdgcn_update_dpp(0, __float_as_int(x), CTRL, 0xf, 0xf, true);
    return x + __int_as_float(t);
}
__device__ inline float wave_sum64(float x) {
    x = dpp_add<0x111>(x);   // row_shr:1
    x = dpp_add<0x112>(x);   // row_shr:2
    x = dpp_add<0x114>(x);   // row_shr:4
    x = dpp_add<0x118>(x);   // row_shr:8
    x = dpp_add<0x142>(x);   // row_bcast:15
    x = dpp_add<0x143>(x);   // row_bcast:31
    return __int_as_float(__builtin_amdgcn_readlane(__float_as_int(x), 63));
}

// ---------------------------------------------------------------------------
// k_pre: blocks 0..1562 -> node_proj = node_raw @ W_feat + b_feat, skill = (int)raw[:,0]
//        last block     -> WgT[dj][dk] = bf16(ln_g[dk]*W_gcn[dk][dj]), hb = ln_b @ W_gcn
// ---------------------------------------------------------------------------
__global__ __launch_bounds__(256) void k_pre(
    const float* __restrict__ node_raw, const float* __restrict__ W_feat,
    const float* __restrict__ b_feat, const float* __restrict__ W_gcn,
    const float* __restrict__ ln_g, const float* __restrict__ ln_b,
    float* __restrict__ proj, int* __restrict__ skill,
    unsigned short* __restrict__ WgT, float* __restrict__ hb)
{
    __shared__ float red[4][64];
    __shared__ float Ws[128 * 64];          // 32 KiB staged W_feat
    int blk = blockIdx.x;
    int t = threadIdx.x;
    int dj = t & 63;

    if (blk == gridDim.x - 1) {             // params block
        int g = t >> 6;                     // dk quarter
        float acc = 0.f;
        #pragma unroll
        for (int i = 0; i < 16; ++i) {
            int dk = g * 16 + i;
            float wv = W_gcn[dk * 64 + dj];
            WgT[dj * 64 + dk] = f2bf(ln_g[dk] * wv);
            acc += ln_b[dk] * wv;
        }
        red[g][dj] = acc;
        __syncthreads();
        if (g == 0) hb[dj] = red[0][dj] + red[1][dj] + red[2][dj] + red[3][dj];
        return;
    }

    // stage W_feat (128x64 f32 = 8192 elems): 32 coalesced rounds
    #pragma unroll
    for (int i = 0; i < 32; ++i) Ws[t + i * 256] = W_feat[t + i * 256];
    __syncthreads();

    int rg = t >> 6;
    int r0 = blk * 32 + rg * 8;
    float acc[8];
    #pragma unroll
    for (int r = 0; r < 8; ++r) acc[r] = 0.f;

    for (int k = 0; k < 128; k += 4) {
        float w0 = Ws[(k + 0) * 64 + dj];
        float w1 = Ws[(k + 1) * 64 + dj];
        float w2 = Ws[(k + 2) * 64 + dj];
        float w3 = Ws[(k + 3) * 64 + dj];
        #pragma unroll
        for (int r = 0; r < 8; ++r) {
            int row = r0 + r;
            int rc = row < NUM_NODES ? row : (NUM_NODES - 1);
            f32x4 rv = *(const f32x4*)(node_raw + (size_t)rc * 128 + k);
            acc[r] += rv.x * w0 + rv.y * w1 + rv.z * w2 + rv.w * w3;
        }
    }
    float bfv = b_feat[dj];
    #pragma unroll
    for (int r = 0; r < 8; ++r) {
        int row = r0 + r;
        if (row < NUM_NODES) proj[(size_t)row * 64 + dj] = acc[r] + bfv;
    }
    if (t < 32) {
        int row = blk * 32 + t;
        if (row < NUM_NODES) skill[row] = (int)node_raw[(size_t)row * 128];
    }
}

// ---------------------------------------------------------------------------
// k_main: one block per sample b. 256 threads = 4 waves. (R6 structure:
//   DPP LN + 5-deep pipelined proj gather.)
// ---------------------------------------------------------------------------
__global__ __launch_bounds__(256) void k_main(
    const int* __restrict__ ids, const int* __restrict__ eids,
    const float* __restrict__ times, const int* __restrict__ dst_ids,
    const float* __restrict__ edge_raw,
    const float* __restrict__ W_edge, const float* __restrict__ b_edge,
    const float* __restrict__ W_time, const float* __restrict__ b_time,
    const float* __restrict__ W_struct, const float* __restrict__ b_struct,
    const float* __restrict__ w_tenc, const float* __restrict__ b_tenc,
    const float* __restrict__ b_gcn, const float* __restrict__ W_out,
    const float* __restrict__ b_out,
    const float* __restrict__ proj, const int* __restrict__ skill,
    const unsigned short* __restrict__ WgT, const float* __restrict__ hb,
    float* __restrict__ out)
{
    __shared__ int ids_s[N_];
    __shared__ f32x2 ec_s[N_];                // (edge_col, struct_count)
    __shared__ float tenc_s[N_][8];
    __shared__ unsigned short xh[112 * 64];   // bf16, 16B-chunk XOR-swizzled per row
    __shared__ float pooled[64];
    __shared__ float x2[64];
    __shared__ int vcnt_w[4];

    int b = blockIdx.x;
    int t = threadIdx.x;
    int lane = t & 63, w = t >> 6;

    int dstb = dst_ids[b];
    int skdst = skill[dstb];

    // per-lane params (uniform-address -> scalar loads)
    float wedge = W_edge[lane], wstr = W_struct[lane];
    float biasr = b_edge[lane] + b_time[lane] + 2.f * b_struct[lane];
    float wt[8], bt[8], wtime[8];
    #pragma unroll
    for (int i = 0; i < 8; ++i) {
        wt[i] = w_tenc[i]; bt[i] = b_tenc[i]; wtime[i] = W_time[i * 64 + lane];
    }

    // -------- Stage: per-neighbor scalars --------
    int idx_c = t < N_ ? t : N_ - 1;
    int id_t = ids[b * N_ + idx_c];
    float tm_t = times[b * N_ + idx_c];
    int ei_t = eids[b * N_ + idx_c];
    float e_t = edge_raw[(size_t)ei_t * 128];
    int sk_t = skill[id_t];
    unsigned long long bal = __ballot((t < N_) && (id_t > 0));
    if (lane == 0) vcnt_w[w] = __popcll(bal);
    if (t < N_) {
        ids_s[t] = id_t;
        float c = (id_t == dstb ? 1.f : 0.f) + (sk_t == skdst ? 1.f : 0.f);
        f32x2 ec = {e_t, c};
        ec_s[t] = ec;
        #pragma unroll
        for (int i = 0; i < 8; ++i) tenc_s[t][i] = __cosf(fmaf(tm_t, wt[i], bt[i]));
    }
    if (t < 96) {                              // zero pad xh rows 100..111 (1536B)
        f32x4 z = {0.f, 0.f, 0.f, 0.f};
        *(f32x4*)((char*)xh + 100 * 128 + t * 16) = z;
    }
    if (w == 2) x2[lane] = proj[(size_t)dstb * 64 + lane];
    __syncthreads();
    int v = vcnt_w[0] + vcnt_w[1] + vcnt_w[2] + vcnt_w[3];

    // -------- Phase A: 5-deep pipelined proj gather --------
    float pc[5], pn[5];
    #pragma unroll
    for (int j = 0; j < 5; ++j)
        pc[j] = proj[(size_t)ids_s[j * 4 + w] * 64 + lane];

    #pragma unroll
    for (int g = 0; g < 5; ++g) {
        if (g < 4) {
            #pragma unroll
            for (int j = 0; j < 5; ++j)
                pn[j] = proj[(size_t)ids_s[(5 * (g + 1) + j) * 4 + w] * 64 + lane];
        }
        #pragma unroll
        for (int j = 0; j < 5; ++j) {
            int n = (5 * g + j) * 4 + w;
            f32x2 ec = ec_s[n];
            f32x4 t0 = *(const f32x4*)&tenc_s[n][0];
            f32x4 t1 = *(const f32x4*)&tenc_s[n][4];
            float tf = t0.x * wtime[0];
            tf = fmaf(t0.y, wtime[1], tf);
            tf = fmaf(t0.z, wtime[2], tf);
            tf = fmaf(t0.w, wtime[3], tf);
            tf = fmaf(t1.x, wtime[4], tf);
            tf = fmaf(t1.y, wtime[5], tf);
            tf = fmaf(t1.z, wtime[6], tf);
            tf = fmaf(t1.w, wtime[7], tf);
            float fused = pc[j] + fmaf(ec.x, wedge, tf) + fmaf(ec.y, wstr, biasr);

            // LN across the 64-lane wave — DPP on the VALU pipe
            float s1 = wave_sum64(fused);
            float s2 = wave_sum64(fused * fused);
            float mu = s1 * (1.f / 64.f);
            float var = s2 * (1.f / 64.f) - mu * mu;
            float xhv = (fused - mu) * rsqrtf(var + 1e-5f);
            int chunk = (lane >> 3) ^ (n & 7);
            *(unsigned short*)((char*)xh + n * 128 + chunk * 16 + (lane & 7) * 2) = f2bf(xhv);
        }
        #pragma unroll
        for (int j = 0; j < 5; ++j) pc[j] = pn[j];
    }
    __syncthreads();

    // -------- Phase B: MFMA --------
    int col = 16 * w + (lane & 15);
    int kg = lane >> 4;
    s16x8 bfr0 = *(const s16x8*)(WgT + col * 64 + 0 * 32 + kg * 8);
    s16x8 bfr1 = *(const s16x8*)(WgT + col * 64 + 1 * 32 + kg * 8);

    f32x4 acc[7];
    #pragma unroll
    for (int mt = 0; mt < 7; ++mt) { f32x4 z = {0.f,0.f,0.f,0.f}; acc[mt] = z; }
    #pragma unroll
    for (int mt = 0; mt < 7; ++mt) {
        int row = mt * 16 + (lane & 15);
        int ch0 = (0 * 4 + kg) ^ (row & 7);
        int ch1 = (1 * 4 + kg) ^ (row & 7);
        s16x8 a0 = *(const s16x8*)((char*)xh + row * 128 + ch0 * 16);
        acc[mt] = __builtin_amdgcn_mfma_f32_16x16x32_bf16(a0, bfr0, acc[mt], 0, 0, 0);
        s16x8 a1 = *(const s16x8*)((char*)xh + row * 128 + ch1 * 16);
        acc[mt] = __builtin_amdgcn_mfma_f32_16x16x32_bf16(a1, bfr1, acc[mt], 0, 0, 0);
    }

    // -------- Phase C: chain + relu + pool --------
    float hbv = hb[col], bgc = b_gcn[col];
    float carry = 0.f, po = 0.f;
    #pragma unroll
    for (int mt = 0; mt < 7; ++mt) {
        float hh[4];
        hh[0] = acc[mt].x + hbv; hh[1] = acc[mt].y + hbv;
        hh[2] = acc[mt].z + hbv; hh[3] = acc[mt].w + hbv;
        float hup = __shfl_up(hh[3], 16, 64);
        float hpj = (kg > 0) ? hup : carry;
        int nb = mt * 16 + kg * 4;
        #pragma unroll
        for (int j = 0; j < 4; ++j) {
            int nn = nb + j;
            bool hin = (nn >= 1) && (nn < v);
            float a_ = hin ? 0.5f : 1.f;
            float dprev = (nn >= 2 && nn <= v) ? 0.70710678118f : 1.f;
            float coef = hin ? dprev * 0.70710678118f : 0.f;
            float o = hh[j] * a_ + coef * hpj + bgc;
            po += (nn < N_) ? fmaxf(o, 0.f) : 0.f;
            hpj = hh[j];
        }
        carry = __shfl(hh[3], 48 + (lane & 15), 64);
    }
    po += __shfl_xor(po, 16, 64);
    po += __shfl_xor(po, 32, 64);
    if (lane < 16) pooled[col] = po * (1.f / (float)N_);
    __syncthreads();

    // -------- Phase D: output projections --------
    if (w == 0) {
        float o = b_out[lane];
        #pragma unroll 8
        for (int dk = 0; dk < 64; ++dk) o = fmaf(pooled[dk], W_out[dk * 64 + lane], o);
        out[(size_t)b * 64 + lane] = o;
    } else if (w == 1) {
        float o = b_out[lane];
        #pragma unroll 8
        for (int dk = 0; dk < 64; ++dk) o = fmaf(x2[dk], W_out[dk * 64 + lane], o);
        out[(size_t)(B_ + b) * 64 + lane] = o;
    }
}

// ---------------------------------------------------------------------------
// MEASUREMENT ROUND: k_pre launched 3x (idempotent) to expose its duration:
//   dur = k_main + 3*k_pre  (baseline R6: k_main + k_pre = 115.6 us)
// ---------------------------------------------------------------------------
extern "C" void kernel_launch(void* const* d_in, const int* in_sizes, int n_in,
                              void* d_out, int out_size, void* d_ws, size_t ws_size,
                              hipStream_t stream)
{
    const int*   ids      = (const int*)d_in[0];
    const int*   eids     = (const int*)d_in[1];
    const float* times    = (const float*)d_in[2];
    const int*   dst_ids  = (const int*)d_in[3];
    const float* node_raw = (const float*)d_in[4];
    const float* edge_raw = (const float*)d_in[5];
    const float* W_feat   = (const float*)d_in[6];
    const float* b_feat   = (const float*)d_in[7];
    const float* W_edge   = (const float*)d_in[8];
    const float* b_edge   = (const float*)d_in[9];
    const float* W_time   = (const float*)d_in[10];
    const float* b_time   = (const float*)d_in[11];
    const float* W_struct = (const float*)d_in[12];
    const float* b_struct = (const float*)d_in[13];
    const float* w_tenc   = (const float*)d_in[14];
    const float* b_tenc   = (const float*)d_in[15];
    const float* ln_g     = (const float*)d_in[16];
    const float* ln_b     = (const float*)d_in[17];
    const float* W_gcn    = (const float*)d_in[18];
    const float* b_gcn    = (const float*)d_in[19];
    const float* W_out    = (const float*)d_in[20];
    const float* b_out    = (const float*)d_in[21];

    char* ws = (char*)d_ws;
    float*          proj   = (float*)ws;                          // 12,800,000 B
    int*            skill  = (int*)(ws + 12800000);               //    200,000 B
    unsigned short* WgT    = (unsigned short*)(ws + 13000000);    //      8,192 B
    float*          hb     = (float*)(ws + 13008192);             //        256 B

    k_pre<<<1564, 256, 0, stream>>>(node_raw, W_feat, b_feat, W_gcn, ln_g, ln_b,
                                    proj, skill, WgT, hb);
    k_pre<<<1564, 256, 0, stream>>>(node_raw, W_feat, b_feat, W_gcn, ln_g, ln_b,
                                    proj, skill, WgT, hb);
    k_pre<<<1564, 256, 0, stream>>>(node_raw, W_feat, b_feat, W_gcn, ln_g, ln_b,
                                    proj, skill, WgT, hb);
    k_main<<<B_, 256, 0, stream>>>(ids, eids, times, dst_ids, edge_raw,
                                   W_edge, b_edge, W_time, b_time, W_struct, b_struct,
                                   w_tenc, b_tenc, b_gcn, W_out, b_out,
                                   proj, skill, WgT, hb, (float*)d_out);
}

// Round 10
// 65.946 us; speedup vs baseline: 3.5602x; 3.5602x over previous
//
#include <hip/hip_runtime.h>
#include <stdint.h>

#define NUM_NODES 50000
#define B_ 4096
#define N_ 100

typedef float f32x4 __attribute__((ext_vector_type(4)));
typedef float f32x2 __attribute__((ext_vector_type(2)));
typedef short s16x8 __attribute__((ext_vector_type(8)));

__device__ inline unsigned short f2bf(float f) {
    unsigned u = __float_as_uint(f);
    u += 0x7fffu + ((u >> 16) & 1u);
    return (unsigned short)(u >> 16);
}

// wave64 sum-reduce on the VALU pipe (DPP), result broadcast to all lanes.
template <int CTRL>
__device__ inline float dpp_add(float x) {
    int t = __builtin_amdgcn_update_dpp(0, __float_as_int(x), CTRL, 0xf, 0xf, true);
    return x + __int_as_float(t);
}
__device__ inline float wave_sum64(float x) {
    x = dpp_add<0x111>(x);   // row_shr:1
    x = dpp_add<0x112>(x);   // row_shr:2
    x = dpp_add<0x114>(x);   // row_shr:4
    x = dpp_add<0x118>(x);   // row_shr:8
    x = dpp_add<0x142>(x);   // row_bcast:15
    x = dpp_add<0x143>(x);   // row_bcast:31
    return __int_as_float(__builtin_amdgcn_readlane(__float_as_int(x), 63));
}

// ---------------------------------------------------------------------------
// k_pre (MFMA): blocks 0..781 -> proj = node_raw @ W_feat + b_feat (64 rows/blk),
//               skill = (int)node_raw[:,0]
//               last block -> WgT[dj][dk] = bf16(ln_g[dk]*W_gcn[dk][dj]), hb
// A-frag: per-lane coalesced f32x8 global load + bf16 cvt.
// B-frag: W_feat prepacked per-lane in LDS (frag-ready, conflict-free b128).
// ---------------------------------------------------------------------------
__global__ __launch_bounds__(256) void k_pre(
    const float* __restrict__ node_raw, const float* __restrict__ W_feat,
    const float* __restrict__ b_feat, const float* __restrict__ W_gcn,
    const float* __restrict__ ln_g, const float* __restrict__ ln_b,
    float* __restrict__ proj, int* __restrict__ skill,
    unsigned short* __restrict__ WgT, float* __restrict__ hb)
{
    __shared__ float red[4][64];
    __shared__ unsigned short WfB[16][64][8];   // [ct*4+kt][lane][8] bf16, 16 KiB
    int blk = blockIdx.x;
    int t = threadIdx.x;
    int dj = t & 63;

    if (blk == gridDim.x - 1) {             // params block
        int g = t >> 6;                     // dk quarter
        float acc = 0.f;
        #pragma unroll
        for (int i = 0; i < 16; ++i) {
            int dk = g * 16 + i;
            float wv = W_gcn[dk * 64 + dj];
            WgT[dj * 64 + dk] = f2bf(ln_g[dk] * wv);
            acc += ln_b[dk] * wv;
        }
        red[g][dj] = acc;
        __syncthreads();
        if (g == 0) hb[dj] = red[0][dj] + red[1][dj] + red[2][dj] + red[3][dj];
        return;
    }

    // stage W_feat frag-ready: entry e = tile*64 + l, tile = ct*4 + kt
    #pragma unroll
    for (int i = 0; i < 4; ++i) {
        int e = t + i * 256;
        int tile = e >> 6;
        int l = e & 63;
        int ct = tile >> 2, kt = tile & 3;
        int col = ct * 16 + (l & 15);
        int ks = kt * 32 + (l >> 4) * 8;
        s16x8 a;
        #pragma unroll
        for (int j = 0; j < 8; ++j)
            a[j] = (short)f2bf(W_feat[(ks + j) * 64 + col]);
        *(s16x8*)&WfB[tile][l][0] = a;
    }
    __syncthreads();

    int w = t >> 6, lane = t & 63;
    int rbase = blk * 64 + w * 16;
    int rA = rbase + (lane & 15);
    int rc = rA < NUM_NODES ? rA : (NUM_NODES - 1);
    int kq = lane >> 4;

    // A fragments: lane = row(lane&15), k = kt*32 + kq*8 .. +8 (coalesced f32x8)
    s16x8 A[4];
    float a0x = 0.f;
    #pragma unroll
    for (int kt = 0; kt < 4; ++kt) {
        const float* src = node_raw + (size_t)rc * 128 + kt * 32 + kq * 8;
        f32x4 v0 = *(const f32x4*)src;
        f32x4 v1 = *(const f32x4*)(src + 4);
        s16x8 a;
        a[0] = (short)f2bf(v0.x); a[1] = (short)f2bf(v0.y);
        a[2] = (short)f2bf(v0.z); a[3] = (short)f2bf(v0.w);
        a[4] = (short)f2bf(v1.x); a[5] = (short)f2bf(v1.y);
        a[6] = (short)f2bf(v1.z); a[7] = (short)f2bf(v1.w);
        A[kt] = a;
        if (kt == 0) a0x = v0.x;
    }
    if (kq == 0 && rA < NUM_NODES) skill[rA] = (int)a0x;   // k=0 column, exact f32

    f32x4 acc[4];
    #pragma unroll
    for (int ct = 0; ct < 4; ++ct) { f32x4 z = {0.f,0.f,0.f,0.f}; acc[ct] = z; }
    #pragma unroll
    for (int ct = 0; ct < 4; ++ct) {
        #pragma unroll
        for (int kt = 0; kt < 4; ++kt) {
            s16x8 bfr = *(const s16x8*)&WfB[ct * 4 + kt][lane][0];
            acc[ct] = __builtin_amdgcn_mfma_f32_16x16x32_bf16(A[kt], bfr, acc[ct], 0, 0, 0);
        }
    }

    // C: col = lane&15 (+16*ct), row = rbase + kq*4 + j
    #pragma unroll
    for (int ct = 0; ct < 4; ++ct) {
        int col = ct * 16 + (lane & 15);
        float bf = b_feat[col];
        #pragma unroll
        for (int j = 0; j < 4; ++j) {
            int row = rbase + kq * 4 + j;
            if (row < NUM_NODES)
                proj[(size_t)row * 64 + col] = acc[ct][j] + bf;
        }
    }
}

// ---------------------------------------------------------------------------
// k_main: one block per sample b. 256 threads = 4 waves. (R6 structure:
//   DPP LN + 5-deep pipelined proj gather.)
// ---------------------------------------------------------------------------
__global__ __launch_bounds__(256) void k_main(
    const int* __restrict__ ids, const int* __restrict__ eids,
    const float* __restrict__ times, const int* __restrict__ dst_ids,
    const float* __restrict__ edge_raw,
    const float* __restrict__ W_edge, const float* __restrict__ b_edge,
    const float* __restrict__ W_time, const float* __restrict__ b_time,
    const float* __restrict__ W_struct, const float* __restrict__ b_struct,
    const float* __restrict__ w_tenc, const float* __restrict__ b_tenc,
    const float* __restrict__ b_gcn, const float* __restrict__ W_out,
    const float* __restrict__ b_out,
    const float* __restrict__ proj, const int* __restrict__ skill,
    const unsigned short* __restrict__ WgT, const float* __restrict__ hb,
    float* __restrict__ out)
{
    __shared__ int ids_s[N_];
    __shared__ f32x2 ec_s[N_];                // (edge_col, struct_count)
    __shared__ float tenc_s[N_][8];
    __shared__ unsigned short xh[112 * 64];   // bf16, 16B-chunk XOR-swizzled per row
    __shared__ float pooled[64];
    __shared__ float x2[64];
    __shared__ int vcnt_w[4];

    int b = blockIdx.x;
    int t = threadIdx.x;
    int lane = t & 63, w = t >> 6;

    int dstb = dst_ids[b];
    int skdst = skill[dstb];

    // per-lane params (uniform-address -> scalar loads)
    float wedge = W_edge[lane], wstr = W_struct[lane];
    float biasr = b_edge[lane] + b_time[lane] + 2.f * b_struct[lane];
    float wt[8], bt[8], wtime[8];
    #pragma unroll
    for (int i = 0; i < 8; ++i) {
        wt[i] = w_tenc[i]; bt[i] = b_tenc[i]; wtime[i] = W_time[i * 64 + lane];
    }

    // -------- Stage: per-neighbor scalars --------
    int idx_c = t < N_ ? t : N_ - 1;
    int id_t = ids[b * N_ + idx_c];
    float tm_t = times[b * N_ + idx_c];
    int ei_t = eids[b * N_ + idx_c];
    float e_t = edge_raw[(size_t)ei_t * 128];
    int sk_t = skill[id_t];
    unsigned long long bal = __ballot((t < N_) && (id_t > 0));
    if (lane == 0) vcnt_w[w] = __popcll(bal);
    if (t < N_) {
        ids_s[t] = id_t;
        float c = (id_t == dstb ? 1.f : 0.f) + (sk_t == skdst ? 1.f : 0.f);
        f32x2 ec = {e_t, c};
        ec_s[t] = ec;
        #pragma unroll
        for (int i = 0; i < 8; ++i) tenc_s[t][i] = __cosf(fmaf(tm_t, wt[i], bt[i]));
    }
    if (t < 96) {                              // zero pad xh rows 100..111 (1536B)
        f32x4 z = {0.f, 0.f, 0.f, 0.f};
        *(f32x4*)((char*)xh + 100 * 128 + t * 16) = z;
    }
    if (w == 2) x2[lane] = proj[(size_t)dstb * 64 + lane];
    __syncthreads();
    int v = vcnt_w[0] + vcnt_w[1] + vcnt_w[2] + vcnt_w[3];

    // -------- Phase A: 5-deep pipelined proj gather --------
    float pc[5], pn[5];
    #pragma unroll
    for (int j = 0; j < 5; ++j)
        pc[j] = proj[(size_t)ids_s[j * 4 + w] * 64 + lane];

    #pragma unroll
    for (int g = 0; g < 5; ++g) {
        if (g < 4) {
            #pragma unroll
            for (int j = 0; j < 5; ++j)
                pn[j] = proj[(size_t)ids_s[(5 * (g + 1) + j) * 4 + w] * 64 + lane];
        }
        #pragma unroll
        for (int j = 0; j < 5; ++j) {
            int n = (5 * g + j) * 4 + w;
            f32x2 ec = ec_s[n];
            f32x4 t0 = *(const f32x4*)&tenc_s[n][0];
            f32x4 t1 = *(const f32x4*)&tenc_s[n][4];
            float tf = t0.x * wtime[0];
            tf = fmaf(t0.y, wtime[1], tf);
            tf = fmaf(t0.z, wtime[2], tf);
            tf = fmaf(t0.w, wtime[3], tf);
            tf = fmaf(t1.x, wtime[4], tf);
            tf = fmaf(t1.y, wtime[5], tf);
            tf = fmaf(t1.z, wtime[6], tf);
            tf = fmaf(t1.w, wtime[7], tf);
            float fused = pc[j] + fmaf(ec.x, wedge, tf) + fmaf(ec.y, wstr, biasr);

            // LN across the 64-lane wave — DPP on the VALU pipe
            float s1 = wave_sum64(fused);
            float s2 = wave_sum64(fused * fused);
            float mu = s1 * (1.f / 64.f);
            float var = s2 * (1.f / 64.f) - mu * mu;
            float xhv = (fused - mu) * rsqrtf(var + 1e-5f);
            int chunk = (lane >> 3) ^ (n & 7);
            *(unsigned short*)((char*)xh + n * 128 + chunk * 16 + (lane & 7) * 2) = f2bf(xhv);
        }
        #pragma unroll
        for (int j = 0; j < 5; ++j) pc[j] = pn[j];
    }
    __syncthreads();

    // -------- Phase B: MFMA --------
    int col = 16 * w + (lane & 15);
    int kg = lane >> 4;
    s16x8 bfr0 = *(const s16x8*)(WgT + col * 64 + 0 * 32 + kg * 8);
    s16x8 bfr1 = *(const s16x8*)(WgT + col * 64 + 1 * 32 + kg * 8);

    f32x4 acc[7];
    #pragma unroll
    for (int mt = 0; mt < 7; ++mt) { f32x4 z = {0.f,0.f,0.f,0.f}; acc[mt] = z; }
    #pragma unroll
    for (int mt = 0; mt < 7; ++mt) {
        int row = mt * 16 + (lane & 15);
        int ch0 = (0 * 4 + kg) ^ (row & 7);
        int ch1 = (1 * 4 + kg) ^ (row & 7);
        s16x8 a0 = *(const s16x8*)((char*)xh + row * 128 + ch0 * 16);
        acc[mt] = __builtin_amdgcn_mfma_f32_16x16x32_bf16(a0, bfr0, acc[mt], 0, 0, 0);
        s16x8 a1 = *(const s16x8*)((char*)xh + row * 128 + ch1 * 16);
        acc[mt] = __builtin_amdgcn_mfma_f32_16x16x32_bf16(a1, bfr1, acc[mt], 0, 0, 0);
    }

    // -------- Phase C: chain + relu + pool --------
    float hbv = hb[col], bgc = b_gcn[col];
    float carry = 0.f, po = 0.f;
    #pragma unroll
    for (int mt = 0; mt < 7; ++mt) {
        float hh[4];
        hh[0] = acc[mt].x + hbv; hh[1] = acc[mt].y + hbv;
        hh[2] = acc[mt].z + hbv; hh[3] = acc[mt].w + hbv;
        float hup = __shfl_up(hh[3], 16, 64);
        float hpj = (kg > 0) ? hup : carry;
        int nb = mt * 16 + kg * 4;
        #pragma unroll
        for (int j = 0; j < 4; ++j) {
            int nn = nb + j;
            bool hin = (nn >= 1) && (nn < v);
            float a_ = hin ? 0.5f : 1.f;
            float dprev = (nn >= 2 && nn <= v) ? 0.70710678118f : 1.f;
            float coef = hin ? dprev * 0.70710678118f : 0.f;
            float o = hh[j] * a_ + coef * hpj + bgc;
            po += (nn < N_) ? fmaxf(o, 0.f) : 0.f;
            hpj = hh[j];
        }
        carry = __shfl(hh[3], 48 + (lane & 15), 64);
    }
    po += __shfl_xor(po, 16, 64);
    po += __shfl_xor(po, 32, 64);
    if (lane < 16) pooled[col] = po * (1.f / (float)N_);
    __syncthreads();

    // -------- Phase D: output projections --------
    if (w == 0) {
        float o = b_out[lane];
        #pragma unroll 8
        for (int dk = 0; dk < 64; ++dk) o = fmaf(pooled[dk], W_out[dk * 64 + lane], o);
        out[(size_t)b * 64 + lane] = o;
    } else if (w == 1) {
        float o = b_out[lane];
        #pragma unroll 8
        for (int dk = 0; dk < 64; ++dk) o = fmaf(x2[dk], W_out[dk * 64 + lane], o);
        out[(size_t)(B_ + b) * 64 + lane] = o;
    }
}

// ---------------------------------------------------------------------------
extern "C" void kernel_launch(void* const* d_in, const int* in_sizes, int n_in,
                              void* d_out, int out_size, void* d_ws, size_t ws_size,
                              hipStream_t stream)
{
    const int*   ids      = (const int*)d_in[0];
    const int*   eids     = (const int*)d_in[1];
    const float* times    = (const float*)d_in[2];
    const int*   dst_ids  = (const int*)d_in[3];
    const float* node_raw = (const float*)d_in[4];
    const float* edge_raw = (const float*)d_in[5];
    const float* W_feat   = (const float*)d_in[6];
    const float* b_feat   = (const float*)d_in[7];
    const float* W_edge   = (const float*)d_in[8];
    const float* b_edge   = (const float*)d_in[9];
    const float* W_time   = (const float*)d_in[10];
    const float* b_time   = (const float*)d_in[11];
    const float* W_struct = (const float*)d_in[12];
    const float* b_struct = (const float*)d_in[13];
    const float* w_tenc   = (const float*)d_in[14];
    const float* b_tenc   = (const float*)d_in[15];
    const float* ln_g     = (const float*)d_in[16];
    const float* ln_b     = (const float*)d_in[17];
    const float* W_gcn    = (const float*)d_in[18];
    const float* b_gcn    = (const float*)d_in[19];
    const float* W_out    = (const float*)d_in[20];
    const float* b_out    = (const float*)d_in[21];

    char* ws = (char*)d_ws;
    float*          proj   = (float*)ws;                          // 12,800,000 B
    int*            skill  = (int*)(ws + 12800000);               //    200,000 B
    unsigned short* WgT    = (unsigned short*)(ws + 13000000);    //      8,192 B
    float*          hb     = (float*)(ws + 13008192);             //        256 B

    k_pre<<<783, 256, 0, stream>>>(node_raw, W_feat, b_feat, W_gcn, ln_g, ln_b,
                                   proj, skill, WgT, hb);
    k_main<<<B_, 256, 0, stream>>>(ids, eids, times, dst_ids, edge_raw,
                                   W_edge, b_edge, W_time, b_time, W_struct, b_struct,
                                   w_tenc, b_tenc, b_gcn, W_out, b_out,
                                   proj, skill, WgT, hb, (float*)d_out);
}